// Round 12
// baseline (56.293 us; speedup 1.0000x reference)
//
#include <hip/hip_runtime.h>
#include <hip/hip_fp16.h>

#define HW 196
#define C  384
#define CF4 (C/4)          // 96 float4 per row
#define TK 98
#define NT 512
#define NWAVE (NT/64)      // 8
#define RSTRIDE 400        // padded halves per stash row (800 B -> 2-way banks)
#define NSTASH 68          // rows 128..195

__global__ __launch_bounds__(NT, 4) void sampling_kernel(
    const float* __restrict__ token,
    const float* __restrict__ feature,
    float* __restrict__ out)
{
    __shared__ __half stash[NSTASH * RSTRIDE];   // 54.4 KB, rows 128..195 fp16
    __shared__ float tokLds[C];
    __shared__ float score[HW];
    __shared__ float wFlag[128];                 // weight (or 0) for reg rows
    __shared__ float selW[TK];
    __shared__ int   selIdx[TK];
    __shared__ int   rank2[2 * HW];
    __shared__ float wsum[NWAVE];
    __shared__ float part[NWAVE][C];             // 12 KB
    __shared__ float s_max, s_winv;

    const int tid  = threadIdx.x;
    const int wave = tid >> 6;
    const int lane = tid & 63;
    const int l8   = lane & 7;         // sub-lane within 8-lane group
    const int g8   = lane >> 3;        // group 0..7 within wave
    const int pair = blockIdx.x;

    const float* tokp = token + (size_t)pair * C;
    const float4* f4base = (const float4*)(feature + (size_t)pair * (HW * C));
    const float4* t4 = (const float4*)tokLds;

    for (int i = tid; i < C; i += NT) tokLds[i] = tokp[i];
    __syncthreads();

    const float scale = 0.05103103630798288f;  // 384^-0.5

    // fp16 copies of this group's two register-resident rows
    uint2 r16[2][12];

    // ---- pass 1a: rows 0..127 -> registers (fp16) + score ----
    #pragma unroll
    for (int it = 0; it < 2; ++it) {
        const int r = it * 64 + wave * 8 + g8;
        const float4* fr = f4base + (size_t)r * CF4 + l8;
        float4 a[12];
        #pragma unroll
        for (int k = 0; k < 12; ++k) a[k] = fr[8 * k];
        float4 acc = make_float4(0.f, 0.f, 0.f, 0.f);
        #pragma unroll
        for (int k = 0; k < 12; ++k) {
            float4 t = t4[l8 + 8 * k];
            acc.x += a[k].x * t.x; acc.y += a[k].y * t.y;
            acc.z += a[k].z * t.z; acc.w += a[k].w * t.w;
            union { uint2 u; __half2 h[2]; } W;
            W.h[0] = __floats2half2_rn(a[k].x, a[k].y);
            W.h[1] = __floats2half2_rn(a[k].z, a[k].w);
            r16[it][k] = W.u;
        }
        float s = (acc.x + acc.y) + (acc.z + acc.w);
        s += __shfl_xor(s, 1, 64);
        s += __shfl_xor(s, 2, 64);
        s += __shfl_xor(s, 4, 64);
        if (l8 == 0) score[r] = s * scale;
    }

    // ---- pass 1b: rows 128..191 -> LDS stash (fp16) + score ----
    {
        const int r = 128 + wave * 8 + g8;
        const float4* fr = f4base + (size_t)r * CF4 + l8;
        __half* srow = &stash[(r - 128) * RSTRIDE];
        float4 a[12];
        #pragma unroll
        for (int k = 0; k < 12; ++k) a[k] = fr[8 * k];
        float4 acc = make_float4(0.f, 0.f, 0.f, 0.f);
        #pragma unroll
        for (int k = 0; k < 12; ++k) {
            float4 t = t4[l8 + 8 * k];
            acc.x += a[k].x * t.x; acc.y += a[k].y * t.y;
            acc.z += a[k].z * t.z; acc.w += a[k].w * t.w;
            union { uint2 u; __half2 h[2]; } W;
            W.h[0] = __floats2half2_rn(a[k].x, a[k].y);
            W.h[1] = __floats2half2_rn(a[k].z, a[k].w);
            *(uint2*)&srow[4 * l8 + 32 * k] = W.u;
        }
        float s = (acc.x + acc.y) + (acc.z + acc.w);
        s += __shfl_xor(s, 1, 64);
        s += __shfl_xor(s, 2, 64);
        s += __shfl_xor(s, 4, 64);
        if (l8 == 0) score[r] = s * scale;
    }
    // tail rows 192..195
    if (wave < 4 && g8 == 0) {
        const int r = 192 + wave;
        const float4* fr = f4base + (size_t)r * CF4 + l8;
        __half* srow = &stash[(r - 128) * RSTRIDE];
        float4 acc = make_float4(0.f, 0.f, 0.f, 0.f);
        #pragma unroll
        for (int k = 0; k < 12; ++k) {
            float4 a = fr[8 * k];
            float4 t = t4[l8 + 8 * k];
            acc.x += a.x * t.x; acc.y += a.y * t.y;
            acc.z += a.z * t.z; acc.w += a.w * t.w;
            union { uint2 u; __half2 h[2]; } W;
            W.h[0] = __floats2half2_rn(a.x, a.y);
            W.h[1] = __floats2half2_rn(a.z, a.w);
            *(uint2*)&srow[4 * l8 + 32 * k] = W.u;
        }
        float s = (acc.x + acc.y) + (acc.z + acc.w);
        s += __shfl_xor(s, 1, 64);
        s += __shfl_xor(s, 2, 64);
        s += __shfl_xor(s, 4, 64);
        if (l8 == 0) score[r] = s * scale;
    }
    __syncthreads();

    // ---- rank-count (threads 0..391, half-range each); wave 7: max ----
    if (tid < 2 * HW) {
        const int i = tid >> 1, h = tid & 1;
        const float si = score[i];
        int cnt = 0;
        const int j0 = h * (HW / 2);
        for (int j = j0; j < j0 + HW / 2; ++j) {
            const float sj = score[j];
            cnt += (int)((sj > si) | ((sj == si) & (j < i)));
        }
        rank2[tid] = cnt;
    } else if (wave == NWAVE - 1) {
        float m = -3.4e38f;
        for (int i = lane; i < HW; i += 64) m = fmaxf(m, score[i]);
        #pragma unroll
        for (int off = 32; off > 0; off >>= 1)
            m = fmaxf(m, __shfl_xor(m, off, 64));
        if (lane == 0) s_max = m;
    }
    __syncthreads();

    // ---- select + compact (softmax denom cancels: w = exp(s - max)) ----
    float w = 0.f;
    if (tid < HW) {
        const int rank = rank2[2 * tid] + rank2[2 * tid + 1];
        float wv = 0.f;
        if (rank < TK) {
            wv = __expf(score[tid] - s_max);
            selIdx[rank] = tid;
            selW[rank]  = wv;
        }
        if (tid < 128) wFlag[tid] = wv;
        w = wv;
    }
    #pragma unroll
    for (int off = 32; off > 0; off >>= 1) w += __shfl_xor(w, off, 64);
    if (lane == 0) wsum[wave] = w;
    __syncthreads();
    if (tid == 0) {
        float s = 0.f;
        #pragma unroll
        for (int i = 0; i < NWAVE; ++i) s += wsum[i];
        s_winv = 1.f / s;
    }
    __syncthreads();

    // ---- pass 2a: register rows. w=0 kills unselected rows (no branch).
    // Reduce across the 8 groups of the wave via xor-shuffles. ----
    {
        const int row0 = wave * 8 + g8;
        const float w0 = wFlag[row0];
        const float w1 = wFlag[64 + row0];
        float4 av[12];
        #pragma unroll
        for (int k = 0; k < 12; ++k) {
            union { uint2 u; __half2 h[2]; } A, B;
            A.u = r16[0][k]; B.u = r16[1][k];
            float2 a0 = __half22float2(A.h[0]), a1 = __half22float2(A.h[1]);
            float2 b0 = __half22float2(B.h[0]), b1 = __half22float2(B.h[1]);
            av[k].x = w0 * a0.x + w1 * b0.x;
            av[k].y = w0 * a0.y + w1 * b0.y;
            av[k].z = w0 * a1.x + w1 * b1.x;
            av[k].w = w0 * a1.y + w1 * b1.y;
        }
        #pragma unroll
        for (int lvl = 8; lvl <= 32; lvl <<= 1) {
            #pragma unroll
            for (int k = 0; k < 12; ++k) {
                av[k].x += __shfl_xor(av[k].x, lvl, 64);
                av[k].y += __shfl_xor(av[k].y, lvl, 64);
                av[k].z += __shfl_xor(av[k].z, lvl, 64);
                av[k].w += __shfl_xor(av[k].w, lvl, 64);
            }
        }
        if (g8 == 0) {
            #pragma unroll
            for (int k = 0; k < 12; ++k)
                *(float4*)&part[wave][4 * l8 + 32 * k] = av[k];
        }
    }
    __syncthreads();

    // ---- pass 2b: stash rows (selected idx >= 128), wave-uniform ----
    float4 acc_a = make_float4(0.f, 0.f, 0.f, 0.f);
    float4 acc_b = make_float4(0.f, 0.f, 0.f, 0.f);
    #pragma unroll
    for (int j = 0; j < 13; ++j) {
        const int i = wave + NWAVE * j;          // 0..103
        if (i < TK) {
            const int r = selIdx[i];
            if (r >= 128) {
                const float wgt = selW[i];
                const __half* row = &stash[(r - 128) * RSTRIDE];
                union { uint2 u; __half2 h[2]; } U;
                U.u = *(const uint2*)&row[4 * lane];
                float2 f0 = __half22float2(U.h[0]);
                float2 f1 = __half22float2(U.h[1]);
                acc_a.x += wgt * f0.x; acc_a.y += wgt * f0.y;
                acc_a.z += wgt * f1.x; acc_a.w += wgt * f1.y;
                if (lane < 32) {
                    union { uint2 u; __half2 h[2]; } V;
                    V.u = *(const uint2*)&row[256 + 4 * lane];
                    float2 g0 = __half22float2(V.h[0]);
                    float2 g1 = __half22float2(V.h[1]);
                    acc_b.x += wgt * g0.x; acc_b.y += wgt * g0.y;
                    acc_b.z += wgt * g1.x; acc_b.w += wgt * g1.y;
                }
            }
        }
    }
    // merge into this wave's partial (wave-local, program-ordered)
    {
        float4* pw = (float4*)&part[wave][0];
        float4 cur = pw[lane];
        cur.x += acc_a.x; cur.y += acc_a.y; cur.z += acc_a.z; cur.w += acc_a.w;
        pw[lane] = cur;
        if (lane < 32) {
            float4 c2 = pw[64 + lane];
            c2.x += acc_b.x; c2.y += acc_b.y; c2.z += acc_b.z; c2.w += acc_b.w;
            pw[64 + lane] = c2;
        }
    }
    __syncthreads();

    // ---- 8-way cross-wave reduction, coalesced store ----
    if (tid < C) {
        float s = 0.f;
        #pragma unroll
        for (int wv = 0; wv < NWAVE; ++wv) s += part[wv][tid];
        out[(size_t)pair * C + tid] = s * s_winv;
    }
}

extern "C" void kernel_launch(void* const* d_in, const int* in_sizes, int n_in,
                              void* d_out, int out_size, void* d_ws, size_t ws_size,
                              hipStream_t stream) {
    const float* token   = (const float*)d_in[0];
    const float* feature = (const float*)d_in[1];
    float* out = (float*)d_out;
    const int pairs = in_sizes[0] / C;   // 8*16*4 = 512
    sampling_kernel<<<pairs, NT, 0, stream>>>(token, feature, out);
}

// Round 13
// 39.470 us; speedup vs baseline: 1.4262x; 1.4262x over previous
//
#include <hip/hip_runtime.h>
#include <hip/hip_fp16.h>

#define HW 196
#define C  384
#define CF4 (C/4)          // 96 float4 per row
#define TK 98
#define NT 512
#define NWAVE (NT/64)      // 8

__global__ __launch_bounds__(NT, 2) void sampling_kernel(
    const float* __restrict__ token,
    const float* __restrict__ feature,
    float* __restrict__ out)
{
    // Full fp16 stash of all 196 rows (147 KB) -> pass 2 is global-free.
    // 1 block/CU; 512 blocks = 2 staggered rounds -> cross-round overlap.
    __shared__ __align__(16) unsigned char stash_raw[HW * C * 2];
    __shared__ float tokLds[C];
    __shared__ float score[HW];
    __shared__ float selW[TK];
    __shared__ int   selIdx[TK];
    __shared__ int   rank2[2 * HW];
    __shared__ float wsum[NWAVE];
    __shared__ float s_max, s_winv;

    __half (*feat16)[C] = (__half(*)[C])stash_raw;
    float  (*part)[C]   = (float(*)[C])stash_raw;   // aliased, barrier-fenced

    const int tid  = threadIdx.x;
    const int wave = tid >> 6;
    const int lane = tid & 63;
    const int l8   = lane & 7;         // sub-lane within 8-lane group
    const int g8   = lane >> 3;        // group 0..7 within wave
    const int pair = blockIdx.x;

    const float* tokp = token + (size_t)pair * C;
    const float4* f4base = (const float4*)(feature + (size_t)pair * (HW * C));
    const float4* t4 = (const float4*)tokLds;

    for (int i = tid; i < C; i += NT) tokLds[i] = tokp[i];
    __syncthreads();

    // this lane's token column-slice in registers (R11-proven)
    float4 tok[12];
    #pragma unroll
    for (int k = 0; k < 12; ++k) tok[k] = t4[l8 + 8 * k];

    const float scale = 0.05103103630798288f;  // 384^-0.5

    // ---- pass 1: 8-lane group per row; 64 groups -> 3 balanced iters.
    // 12 independent float4 loads/lane; EVERY row stashed to LDS as fp16
    // (data already in registers -> bandwidth-free). ----
    #pragma unroll
    for (int it = 0; it < 3; ++it) {
        const int r = it * 64 + wave * 8 + g8;          // 0..191, balanced
        const float4* fr = f4base + (size_t)r * CF4 + l8;
        float4 a[12];
        #pragma unroll
        for (int k = 0; k < 12; ++k) a[k] = fr[8 * k];
        float4 acc = make_float4(0.f, 0.f, 0.f, 0.f);
        #pragma unroll
        for (int k = 0; k < 12; ++k) {
            acc.x += a[k].x * tok[k].x; acc.y += a[k].y * tok[k].y;
            acc.z += a[k].z * tok[k].z; acc.w += a[k].w * tok[k].w;
            union { uint2 u; __half2 h[2]; } W;
            W.h[0] = __floats2half2_rn(a[k].x, a[k].y);
            W.h[1] = __floats2half2_rn(a[k].z, a[k].w);
            *(uint2*)&feat16[r][4 * l8 + 32 * k] = W.u;
        }
        float s = (acc.x + acc.y) + (acc.z + acc.w);
        s += __shfl_xor(s, 1, 64);
        s += __shfl_xor(s, 2, 64);
        s += __shfl_xor(s, 4, 64);
        if (l8 == 0) score[r] = s * scale;
    }
    // tail rows 192..195
    if (wave < 4 && g8 == 0) {
        const int r = 192 + wave;
        const float4* fr = f4base + (size_t)r * CF4 + l8;
        float4 acc = make_float4(0.f, 0.f, 0.f, 0.f);
        #pragma unroll
        for (int k = 0; k < 12; ++k) {
            float4 a = fr[8 * k];
            acc.x += a.x * tok[k].x; acc.y += a.y * tok[k].y;
            acc.z += a.z * tok[k].z; acc.w += a.w * tok[k].w;
            union { uint2 u; __half2 h[2]; } W;
            W.h[0] = __floats2half2_rn(a.x, a.y);
            W.h[1] = __floats2half2_rn(a.z, a.w);
            *(uint2*)&feat16[r][4 * l8 + 32 * k] = W.u;
        }
        float s = (acc.x + acc.y) + (acc.z + acc.w);
        s += __shfl_xor(s, 1, 64);
        s += __shfl_xor(s, 2, 64);
        s += __shfl_xor(s, 4, 64);
        if (l8 == 0) score[r] = s * scale;
    }
    __syncthreads();

    // ---- rank-count (threads 0..391, half-range each); wave 7: max ----
    if (tid < 2 * HW) {
        const int i = tid >> 1, h = tid & 1;
        const float si = score[i];
        int cnt = 0;
        const int j0 = h * (HW / 2);
        for (int j = j0; j < j0 + HW / 2; ++j) {
            const float sj = score[j];
            cnt += (int)((sj > si) | ((sj == si) & (j < i)));
        }
        rank2[tid] = cnt;
    } else if (wave == NWAVE - 1) {
        float m = -3.4e38f;
        for (int i = lane; i < HW; i += 64) m = fmaxf(m, score[i]);
        #pragma unroll
        for (int off = 32; off > 0; off >>= 1)
            m = fmaxf(m, __shfl_xor(m, off, 64));
        if (lane == 0) s_max = m;
    }
    __syncthreads();

    // ---- select + compact (softmax denom cancels: w = exp(s - max)) ----
    float w = 0.f;
    if (tid < HW) {
        const int rank = rank2[2 * tid] + rank2[2 * tid + 1];
        if (rank < TK) {
            w = __expf(score[tid] - s_max);
            selIdx[rank] = tid;
            selW[rank]  = w;
        }
    }
    #pragma unroll
    for (int off = 32; off > 0; off >>= 1) w += __shfl_xor(w, off, 64);
    if (lane == 0) wsum[wave] = w;
    __syncthreads();
    if (tid == 0) {
        float s = 0.f;
        #pragma unroll
        for (int i = 0; i < NWAVE; ++i) s += wsum[i];
        s_winv = 1.f / s;
    }
    __syncthreads();

    // ---- pass 2: weighted sum over 98 selected rows, ALL from LDS.
    // Row index wave-uniform; uint2 (8B) reads, conflict-free. ----
    float4 acc_a = make_float4(0.f, 0.f, 0.f, 0.f);
    float4 acc_b = make_float4(0.f, 0.f, 0.f, 0.f);
    #pragma unroll
    for (int j = 0; j < 13; ++j) {
        const int i = wave + NWAVE * j;          // 0..103
        if (i < TK) {
            const int   r   = selIdx[i];
            const float wgt = selW[i];
            union { uint2 u; __half2 h[2]; } U;
            U.u = *(const uint2*)&feat16[r][4 * lane];
            float2 f0 = __half22float2(U.h[0]);
            float2 f1 = __half22float2(U.h[1]);
            acc_a.x += wgt * f0.x; acc_a.y += wgt * f0.y;
            acc_a.z += wgt * f1.x; acc_a.w += wgt * f1.y;
            if (lane < 32) {
                union { uint2 u; __half2 h[2]; } V;
                V.u = *(const uint2*)&feat16[r][256 + 4 * lane];
                float2 g0 = __half22float2(V.h[0]);
                float2 g1 = __half22float2(V.h[1]);
                acc_b.x += wgt * g0.x; acc_b.y += wgt * g0.y;
                acc_b.z += wgt * g1.x; acc_b.w += wgt * g1.y;
            }
        }
    }
    // all stash reads complete before the region is reused for partials
    __syncthreads();

    float4* pw = (float4*)&part[wave][0];
    pw[lane] = acc_a;
    if (lane < 32) pw[64 + lane] = acc_b;
    __syncthreads();

    // ---- 8-way cross-wave reduction, coalesced store ----
    if (tid < C) {
        float s = 0.f;
        #pragma unroll
        for (int wv = 0; wv < NWAVE; ++wv) s += part[wv][tid];
        out[(size_t)pair * C + tid] = s * s_winv;
    }
}

extern "C" void kernel_launch(void* const* d_in, const int* in_sizes, int n_in,
                              void* d_out, int out_size, void* d_ws, size_t ws_size,
                              hipStream_t stream) {
    const float* token   = (const float*)d_in[0];
    const float* feature = (const float*)d_in[1];
    float* out = (float*)d_out;
    const int pairs = in_sizes[0] / C;   // 8*16*4 = 512
    sampling_kernel<<<pairs, NT, 0, stream>>>(token, feature, out);
}